// Round 1
// baseline (452.535 us; speedup 1.0000x reference)
//
#include <hip/hip_runtime.h>

#define NSHOTS 4
#define NT     512
#define NZ     256
#define NX     256
#define NRECS  128

static constexpr float DTf    = 0.001f;
static constexpr float INVDH2 = 1.0f / (10.0f * 10.0f);

#define KSTEPS 16                 // fused time steps per launch
#define TILE   32                 // interior tile edge
#define EXT    64                 // TILE + 2*KSTEPS
#define RPT    8                  // ext rows per thread (EXT / NWAVES)
#define NWAVES 8
#define BLOCK  512

// lane i <- lane i-1  (left x-neighbor)
__device__ __forceinline__ float nbr_left(float v) {
#if __has_builtin(__builtin_amdgcn_update_dpp)
  return __int_as_float(__builtin_amdgcn_update_dpp(
      0, __float_as_int(v), 0x138 /*WAVE_SHR1*/, 0xf, 0xf, false));
#else
  return __shfl(v, (int)(threadIdx.x & 63) - 1, 64);
#endif
}
// lane i <- lane i+1  (right x-neighbor)
__device__ __forceinline__ float nbr_right(float v) {
#if __has_builtin(__builtin_amdgcn_update_dpp)
  return __int_as_float(__builtin_amdgcn_update_dpp(
      0, __float_as_int(v), 0x130 /*WAVE_SHL1*/, 0xf, 0xf, false));
#else
  return __shfl(v, (int)(threadIdx.x & 63) + 1, 64);
#endif
}

// One launch advances the wavefield KSTEPS steps for all shots.
// Grid: NSHOTS * 8 * 8 workgroups, each owns a TILE x TILE interior tile and
// computes on an EXT x EXT ghost-extended region held in registers.
__global__ __launch_bounds__(BLOCK, 2) void step16(
    const float* __restrict__ inCur, const float* __restrict__ inPrv,
    float* __restrict__ outCur, float* __restrict__ outPrv,
    const float* __restrict__ c2h,        // (vp*DT)^2 / DH^2, [NZ*NX]
    const float* __restrict__ xwav,       // [NSHOTS*NT]
    const int* __restrict__ src_z, const int* __restrict__ src_x,
    const int* __restrict__ rec_z, const int* __restrict__ rec_x,
    float* __restrict__ out,              // [NSHOTS*NT*NRECS]
    int t0)
{
  const int bid  = blockIdx.x;
  const int s    = bid >> 6;
  const int tz   = (bid >> 3) & 7;
  const int tx   = bid & 7;
  const int tid  = threadIdx.x;
  const int w    = tid >> 6;     // wave 0..7 -> z strip
  const int lane = tid & 63;     // x within ext region

  const int gz0 = tz * TILE - KSTEPS;   // ext-region global origin
  const int gx0 = tx * TILE - KSTEPS;
  const int gx  = gx0 + lane;
  const int zb  = w * RPT;

  __shared__ float haloTop[NWAVES][64];     // cur[0] of each wave
  __shared__ float haloBot[NWAVES][64];     // cur[RPT-1] of each wave
  __shared__ float recTile[TILE][TILE + 1]; // interior mirror for receiver gather
  __shared__ int   nRec;
  __shared__ short recR[NRECS];
  __shared__ short recZL[NRECS];
  __shared__ short recXL[NRECS];

  if (tid == 0) nRec = 0;
  __syncthreads();
  if (tid < NRECS) {
    const int rz = rec_z[s * NRECS + tid];
    const int rx = rec_x[s * NRECS + tid];
    const int lz = rz - tz * TILE;
    const int lx = rx - tx * TILE;
    if ((unsigned)lz < (unsigned)TILE && (unsigned)lx < (unsigned)TILE) {
      const int k = atomicAdd(&nRec, 1);
      recR[k]  = (short)tid;
      recZL[k] = (short)lz;
      recXL[k] = (short)lx;
    }
  }

  // Source ownership (inject in every WG whose ext region covers the source —
  // required so halo-region values stay valid).
  const int slz = src_z[s] - gz0;
  const int slx = src_x[s] - gx0;
  const bool srcMine = (slx == lane) && ((unsigned)(slz - zb) < (unsigned)RPT);
  const int  srcI    = slz - zb;

  // Load ext region: cur field (a), prev field (b), c2. OOB -> 0 (Dirichlet pad;
  // out-of-domain cells have c2=0 and stay exactly 0 through all steps).
  float a[RPT], b[RPT], c2[RPT];
  const bool xok = (unsigned)gx < (unsigned)NX;
  #pragma unroll
  for (int i = 0; i < RPT; ++i) {
    const int gz = gz0 + zb + i;
    const bool ok = xok && ((unsigned)gz < (unsigned)NZ);
    const int fidx = (s * NZ + gz) * NX + gx;
    a[i]  = ok ? inCur[fidx] : 0.0f;
    b[i]  = ok ? inPrv[fidx] : 0.0f;
    c2[i] = ok ? c2h[gz * NX + gx] : 0.0f;
  }

  // Prefetch the 16 source amplitudes.
  float amp[KSTEPS];
  #pragma unroll
  for (int t = 0; t < KSTEPS; ++t)
    amp[t] = (xwav[s * NT + t0 + t] * DTf) * DTf;

  auto do_step = [&](float (&cur)[RPT], float (&nxt)[RPT], int tau) {
    // publish z-strip boundary rows
    haloTop[w][lane] = cur[0];
    haloBot[w][lane] = cur[RPT - 1];
    __syncthreads();
    const float up0 = (w > 0)          ? haloBot[w - 1][lane] : 0.0f;
    const float dn7 = (w < NWAVES - 1) ? haloTop[w + 1][lane] : 0.0f;
    #pragma unroll
    for (int i = 0; i < RPT; ++i) {
      const float c  = cur[i];
      const float up = (i == 0)       ? up0 : cur[i - 1];
      const float dn = (i == RPT - 1) ? dn7 : cur[i + 1];
      const float lf = nbr_left(c);
      const float rt = nbr_right(c);
      const float sum = (up + dn) + (lf + rt);
      const float lap = __builtin_fmaf(-4.0f, c, sum);   // sum - 4c
      float v = __builtin_fmaf(2.0f, c, -nxt[i]);        // 2p - p_prev
      v = __builtin_fmaf(c2[i], lap, v);
      if (srcMine && i == srcI) v += amp[tau];
      nxt[i] = v;
    }
    // mirror interior into LDS for receiver gather
    if (w >= 2 && w < 6 && lane >= KSTEPS && lane < KSTEPS + TILE) {
      #pragma unroll
      for (int i = 0; i < RPT; ++i)
        recTile[(w - 2) * RPT + i][lane - KSTEPS] = nxt[i];
    }
    __syncthreads();
    if (tid < nRec) {
      out[(s * NT + (t0 + tau)) * NRECS + recR[tid]] =
          recTile[recZL[tid]][recXL[tid]];
    }
  };

  #pragma unroll
  for (int h = 0; h < KSTEPS / 2; ++h) {
    do_step(a, b, 2 * h);
    do_step(b, a, 2 * h + 1);
  }

  // write back interior of the final two time levels (a = S_{t0+16}, b = S_{t0+15})
  if (w >= 2 && w < 6 && lane >= KSTEPS && lane < KSTEPS + TILE) {
    #pragma unroll
    for (int i = 0; i < RPT; ++i) {
      const int gz = gz0 + zb + i;          // in [tz*32, tz*32+32)
      const int fidx = (s * NZ + gz) * NX + gx;
      outCur[fidx] = a[i];
      outPrv[fidx] = b[i];
    }
  }
}

__global__ void init_c2(const float* __restrict__ vp, float* __restrict__ c2h) {
  const int i = blockIdx.x * blockDim.x + threadIdx.x;
  if (i < NZ * NX) {
    const float t = vp[i] * DTf;            // (vp*DT)^2, then fold 1/DH^2
    c2h[i] = (t * t) * INVDH2;
  }
}

extern "C" void kernel_launch(void* const* d_in, const int* in_sizes, int n_in,
                              void* d_out, int out_size, void* d_ws, size_t ws_size,
                              hipStream_t stream) {
  const float* x     = (const float*)d_in[0];
  const float* vp    = (const float*)d_in[1];
  const int*   src_z = (const int*)d_in[2];
  const int*   src_x = (const int*)d_in[3];
  const int*   rec_z = (const int*)d_in[4];
  const int*   rec_x = (const int*)d_in[5];
  float* out = (float*)d_out;

  // workspace layout: two ping-pong field pairs + c2 table (~4.5 MB total)
  float* ws = (float*)d_ws;
  const size_t F = (size_t)NSHOTS * NZ * NX;   // 262144 floats per field
  float* A0 = ws;            // cur  (pair A)
  float* A1 = ws + F;        // prev (pair A)
  float* B0 = ws + 2 * F;    // cur  (pair B)
  float* B1 = ws + 3 * F;    // prev (pair B)
  float* c2 = ws + 4 * F;

  // zero initial fields (ws is re-poisoned 0xAA before every timed call)
  hipMemsetAsync(A0, 0, 2 * F * sizeof(float), stream);
  init_c2<<<dim3((NZ * NX + 255) / 256), dim3(256), 0, stream>>>(vp, c2);

  for (int j = 0; j < NT / KSTEPS; ++j) {
    const float* ic = (j & 1) ? B0 : A0;
    const float* ip = (j & 1) ? B1 : A1;
    float* oc = (j & 1) ? A0 : B0;
    float* op = (j & 1) ? A1 : B1;
    step16<<<dim3(NSHOTS * 8 * 8), dim3(BLOCK), 0, stream>>>(
        ic, ip, oc, op, c2, x, src_z, src_x, rec_z, rec_x, out, j * KSTEPS);
  }
}